// Round 10
// baseline (123.045 us; speedup 1.0000x reference)
//
#include <hip/hip_runtime.h>

// Problem constants (fixed by reference: B=32,D=64,H=32,W=32,K=2048)
#define N_PIX 32768   // B*H*W
#define DIM   64
#define KCODE 2048

typedef __attribute__((ext_vector_type(8)))  short bf16x8;   // 8 bf16 = 4 VGPR
typedef __attribute__((ext_vector_type(16))) float f32x16;   // 32x32 MFMA C/D

// bf16 round-to-nearest-even (manual, deterministic)
__device__ inline unsigned short f2bf(float v) {
    unsigned int u = __float_as_uint(v);
    return (unsigned short)((u + 0x7FFFu + ((u >> 16) & 1u)) >> 16);
}
__device__ inline float bf2f(unsigned short b) {
    return __uint_as_float(((unsigned int)b) << 16);
}

// ---------------------------------------------------------------------------
// convert_b v2 (UNCHANGED): 16 threads/code, 128 blocks. One coalesced float4
// load per thread, split to 3 bf16 planes, e_sq via width-16 shfl butterfly.
// ---------------------------------------------------------------------------
__global__ __launch_bounds__(256)
void convert_b_kernel(const float* __restrict__ cb, unsigned short* __restrict__ Bg,
                      float* __restrict__ esq) {
    const int t   = blockIdx.x * 256 + threadIdx.x;   // 32768 threads
    const int n   = t >> 4;                           // code id 0..2047
    const int sub = t & 15;                           // 16 thr per code
    const int ntile = n >> 4, ni = n & 15;

    const float4 v = *(const float4*)(cb + (size_t)n * DIM + sub * 4);  // coalesced

    unsigned int h01, h23, m01, m23, l01, l23;
    {
        unsigned short h, m, l;
        float r1;
        h = f2bf(v.x); r1 = v.x - bf2f(h); m = f2bf(r1); l = f2bf(r1 - bf2f(m));
        h01 = h;       m01 = m;       l01 = l;
        h = f2bf(v.y); r1 = v.y - bf2f(h); m = f2bf(r1); l = f2bf(r1 - bf2f(m));
        h01 |= (unsigned int)h << 16; m01 |= (unsigned int)m << 16; l01 |= (unsigned int)l << 16;
        h = f2bf(v.z); r1 = v.z - bf2f(h); m = f2bf(r1); l = f2bf(r1 - bf2f(m));
        h23 = h;       m23 = m;       l23 = l;
        h = f2bf(v.w); r1 = v.w - bf2f(h); m = f2bf(r1); l = f2bf(r1 - bf2f(m));
        h23 |= (unsigned int)h << 16; m23 |= (unsigned int)m << 16; l23 |= (unsigned int)l << 16;
    }

    // e_sq: per-thread partial then width-16 butterfly (pairwise order)
    float s = (v.x * v.x + v.y * v.y) + (v.z * v.z + v.w * v.w);
#pragma unroll
    for (int mk = 1; mk < 16; mk <<= 1) s += __shfl_xor(s, mk, 16);
    if (sub == 0) esq[n] = s;

    // dst: unit (ntile, kb=sub>>1), inner offset ni*16 + (sub&1)*8  — layout
    // identical to r12's Bg (dist kernel reads the same bytes).
    char* outb = (char*)Bg;
    const size_t u = ((((size_t)ntile) * 8 + (sub >> 1)) << 8) + ni * 16 + (sub & 1) * 8;
    uint2 hw2 = {h01, h23}, mw2 = {m01, m23}, lw2 = {l01, l23};
    *(uint2*)(outb + u)          = hw2;               // plane h (stride 256 KB)
    *(uint2*)(outb + 262144 + u) = mw2;               // plane m
    *(uint2*)(outb + 524288 + u) = lw2;               // plane l
}

// MFMA pass at 32x32x16: 4 k-steps, kk-split chains acc[ks&1] (2 chains,
// same-chain distance 2 MFMAs ~65 cyc > MFMA latency).
#define DO_PASS(APL, BPL)                                                    \
    _Pragma("unroll") for (int ks = 0; ks < 4; ++ks)                         \
        acc[ks & 1] = __builtin_amdgcn_mfma_f32_32x32x16_bf16(               \
            af[APL][ks], bfr[BPL][ks], acc[ks & 1], 0, 0, 0);

// In-place streaming reload of ONE B plane for tile JN (4 fragments =
// 4 k-steps) straight from global (Bg is L2-resident). Per-lane address:
// lane l needs code n0+(l&31), dims ks*16+(l>>5)*8..+7 — regrouping of the
// SAME Bg bytes the 16x16 path read (layout byte-identical, coalesced
// 256 B segments). Placed after the plane's LAST consuming pass.
#define RELOAD(PL, JN)                                                       \
    if ((JN) < 16) {                                                         \
      _Pragma("unroll") for (int ks = 0; ks < 4; ++ks)                       \
        bfr[PL][ks] = *(const bf16x8*)(bp0 + (size_t)(JN) * 4096             \
                                       + ks * 512 + (size_t)(PL) * 262144);  \
    }

// One iteration, NO barriers, single B buffer, 24 MFMAs (32 px x 32 codes
// x K=64 x 6 passes). Pass order identical to r12: hl, lh, mm, hm, mh, hh.
// B-plane last uses: B2 @ pass1, B1 @ pass4, B0 @ pass6 -> reload there.
#define ITER(J)                                                              \
  {                                                                          \
    f32x16 acc[2];                                                           \
    _Pragma("unroll") for (int z = 0; z < 16; ++z) { acc[0][z] = 0.f; acc[1][z] = 0.f; } \
    __builtin_amdgcn_s_setprio(1);                                           \
    DO_PASS(0, 2)                                                            \
    RELOAD(2, (J) + 1)                                                       \
    DO_PASS(2, 0)                                                            \
    DO_PASS(1, 1)                                                            \
    DO_PASS(0, 1)                                                            \
    RELOAD(1, (J) + 1)                                                       \
    DO_PASS(1, 0)                                                            \
    DO_PASS(0, 0)                                                            \
    RELOAD(0, (J) + 1)                                                       \
    __builtin_amdgcn_s_setprio(0);                                           \
    const int n = wn * 512 + (J) * 32 + (lane & 31);                         \
    const float e = esqF[n];                                                 \
    _Pragma("unroll") for (int r = 0; r < 16; ++r) {                         \
      float s2 = acc[0][r] + acc[1][r];                                      \
      float d = fmaf(-2.f, s2, e);                                           \
      if (d < best[r]) { best[r] = d; bidx[r] = n; }                         \
    }                                                                        \
  }

// ---------------------------------------------------------------------------
// Fused dist+argmin+gather v11: 32x32x16 MFMA (+20% pipe rate, half the
// MFMA instructions) on v6's 512-thr/8-wave wm x wn geometry. Each wave:
// 32 px x 512-code strip in 16 ITERS of 32 codes — HALF the per-iteration
// serial tails (the r9 diagnosis: tails, not memory, are the 50% pipe
// idle). A-fragments direct global->reg (v10 path, 32 loads/thread);
// B single-buffer streamed global->reg; zero barriers in the loop.
// Fragment maps: A/B row=l&31, k=(l>>5)*8+j; C/D col=lane&31,
// row=(reg&3)+8*(reg>>2)+4*(lane>>5)  [m74/m101-verified].
// VGPR ~175 -> 1 block/CU, 2 waves/SIMD (= m06 pipe-saturating occupancy).
// ---------------------------------------------------------------------------
__global__ __launch_bounds__(512, 2)
void dist_fused_kernel(const float* __restrict__ laten,
                       const unsigned short* __restrict__ Bg,
                       const float* __restrict__ esq,
                       const float* __restrict__ cb,
                       float* __restrict__ out0, float* __restrict__ out1) {
    __shared__ float esqF[2048];                 // 8 KB
    __shared__ float redD[256];                  // [64 px][4 wn]
    __shared__ int   redI[256];
    __shared__ int   idxF[64];

    const int tid  = threadIdx.x;
    const int lane = tid & 63;
    const int wave = tid >> 6;                   // 0..7
    const int wm   = wave & 1;                   // 32-px half
    const int wn   = wave >> 1;                  // 512-code strip
    const int c31  = lane & 31;                  // code offset / A row
    const int hi   = lane >> 5;                  // k-group half
    const int bx = blockIdx.x;
    const int bb = bx >> 4, hw0 = (bx & 15) * 64;   // 64 px contiguous in hw

    const char* BgB = (const char*)Bg;
    // per-lane B base (tile 0, plane 0, ks 0): code wn*512 + c31, dims hi*8
    const char* bp0 = BgB + (size_t)wn * 65536 + (size_t)(c31 >> 4) * 2048
                    + (size_t)hi * 256 + (size_t)(c31 & 15) * 16;

    // ---- A fragments DIRECT global -> registers ----
    // af[pl][ks]: pixel p = wm*32 + c31, dims ks*16 + hi*8 + j (j 0..7).
    // Lanes 0..31 read 32 consecutive floats per (ks,j) — coalesced 128 B.
    bf16x8 af[3][4];
    {
        const int p = wm * 32 + c31;
#pragma unroll
        for (int ks = 0; ks < 4; ++ks) {
            const float* srcA = laten + (size_t)bb * 65536
                              + (size_t)(ks * 16 + hi * 8) * 1024 + hw0 + p;
            bf16x8 hv, mv, lv;
#pragma unroll
            for (int j = 0; j < 8; ++j) {
                float v = srcA[(size_t)j << 10];
                unsigned short h = f2bf(v);
                float r1 = v - bf2f(h);
                unsigned short m = f2bf(r1);
                unsigned short l = f2bf(r1 - bf2f(m));
                hv[j] = (short)h; mv[j] = (short)m; lv[j] = (short)l;
            }
            af[0][ks] = hv;
            af[1][ks] = mv;
            af[2][ks] = lv;
        }
    }

    // ---- stage e_sq to LDS (4 floats/thread, 512 thr -> 2048) ----
    *(float4*)(esqF + tid * 4) = *(const float4*)(esq + tid * 4);
    __syncthreads();

    // ---- prologue: tile 0 into the single register buffer ----
    bf16x8 bfr[3][4];
    RELOAD(2, 0)
    RELOAD(0, 0)
    RELOAD(1, 0)

    float best[16];
    int   bidx[16];
#pragma unroll
    for (int r = 0; r < 16; ++r) { best[r] = 3.4e38f; bidx[r] = 0; }

    // ---- main loop: 16 iters, barrier-free, single-buffer streaming ----
    for (int j = 0; j < 16; ++j) ITER(j)

    // ---- reduce: shfl over the 32 codes (width-32 butterfly, lex ties),
    //      then LDS over the 4 wn strips ----
#pragma unroll
    for (int r = 0; r < 16; ++r) {
        float d = best[r];
        int   i = bidx[r];
#pragma unroll
        for (int m = 1; m < 32; m <<= 1) {
            float od = __shfl_xor(d, m, 32);
            int   oi = __shfl_xor(i, m, 32);
            if (od < d || (od == d && oi < i)) { d = od; i = oi; }
        }
        if (c31 == 0) {
            int p = wm * 32 + (r & 3) + 8 * (r >> 2) + 4 * hi;   // pixel 0..63
            redD[p * 4 + wn] = d;
            redI[p * 4 + wn] = i;
        }
    }
    __syncthreads();

    if (tid < 64) {
        float bd = redD[tid * 4]; int bi = redI[tid * 4];
#pragma unroll
        for (int w = 1; w < 4; ++w) {
            float d = redD[tid * 4 + w]; int i = redI[tid * 4 + w];
            if (d < bd || (d == bd && i < bi)) { bd = d; bi = i; }
        }
        out0[bx * 64 + tid] = (float)bi;
        idxF[tid] = bi;
    }
    __syncthreads();

    // ---- fused gather: 64 px x 64 dims from the ORIGINAL fp32 codebook ----
    const int p = tid & 63, dg = tid >> 6;           // dg: 8 dims each
    const int idx = idxF[p];
    const float4* srcr = (const float4*)(cb + ((size_t)idx << 6) + dg * 8);
    float* o = out1 + (size_t)bb * 65536 + (size_t)dg * 8192 + hw0 + p;
    float4 v0 = srcr[0], v1 = srcr[1];
    o[(size_t)0 << 10] = v0.x; o[(size_t)1 << 10] = v0.y;
    o[(size_t)2 << 10] = v0.z; o[(size_t)3 << 10] = v0.w;
    o[(size_t)4 << 10] = v1.x; o[(size_t)5 << 10] = v1.y;
    o[(size_t)6 << 10] = v1.z; o[(size_t)7 << 10] = v1.w;
}

// ---------------------------------------------------------------------------
extern "C" void kernel_launch(void* const* d_in, const int* in_sizes, int n_in,
                              void* d_out, int out_size, void* d_ws, size_t ws_size,
                              hipStream_t stream) {
    const float* laten = (const float*)d_in[0];   // (32,64,32,32) fp32
    const float* cb    = (const float*)d_in[1];   // (2048,64) fp32

    float* out0 = (float*)d_out;                  // indices as float, N_PIX
    float* out1 = (float*)d_out + N_PIX;          // quant_laten, 2M

    // ws layout: esq 8 KB | Bg 768 KB   (~776 KB total)
    float* esq = (float*)d_ws;
    unsigned short* Bg = (unsigned short*)(esq + 2048);

    convert_b_kernel<<<128, 256, 0, stream>>>(cb, Bg, esq);

    dist_fused_kernel<<<512, 512, 0, stream>>>(laten, Bg, esq, cb, out0, out1);
}